// Round 19
// baseline (392.406 us; speedup 1.0000x reference)
//
#include <hip/hip_runtime.h>
#include <stdint.h>

typedef _Float16 f16;
typedef __bf16 bf16;
typedef f16 f16x4 __attribute__((ext_vector_type(4)));
typedef f16 f16x8 __attribute__((ext_vector_type(8)));
typedef bf16 bf16x4 __attribute__((ext_vector_type(4)));
typedef bf16 bf16x8 __attribute__((ext_vector_type(8)));
typedef float f32x4 __attribute__((ext_vector_type(4)));

#define SEQ 2048
#define HID 4096
#define NH 32
#define NKV 8
#define HD 128
#define NQKV 6144
#define LN127 4.8441870864585870f

__device__ __forceinline__ float fq_round(float x, float s){
  float r = rintf(x / s);
  r = fminf(fmaxf(r, -128.f), 127.f);
  return r * s;
}

__device__ __forceinline__ void gload_lds16(const void* g, void* l){
  __builtin_amdgcn_global_load_lds(
      (const __attribute__((address_space(1))) uint32_t*)g,
      (__attribute__((address_space(3))) uint32_t*)l, 16, 0, 0);
}

// stage a [128 rows][8 granules-of-16B] tile (row = 64 f16/bf16), XOR-swizzled. 256 thr, 4 loads/thread.
__device__ __forceinline__ void stage_g8(const void* gbase, size_t row_bytes, void* lds, int tid){
  int w = tid >> 6, l = tid & 63;
  #pragma unroll
  for (int i = 0; i < 4; i++){
    int flat = i * 256 + w * 64 + l;
    int r = flat >> 3, g = flat & 7;
    const char* src = (const char*)gbase + (size_t)r * row_bytes + (size_t)((g ^ (r & 7)) << 4);
    char* dst = (char*)lds + (size_t)(i * 256 + w * 64) * 16;
    gload_lds16(src, dst);
  }
}
// stage a [64 rows][16 granules-of-16B] tile (row = 128 f16), XOR-swizzled. 256 thr, 4 loads/thread.
__device__ __forceinline__ void stage_g16(const void* gbase, size_t row_bytes, void* lds, int tid){
  int w = tid >> 6, l = tid & 63;
  #pragma unroll
  for (int i = 0; i < 4; i++){
    int flat = i * 256 + w * 64 + l;
    int r = flat >> 4, g = flat & 15;
    const char* src = (const char*)gbase + (size_t)r * row_bytes + (size_t)((g ^ (r & 15)) << 4);
    char* dst = (char*)lds + (size_t)(i * 256 + w * 64) * 16;
    gload_lds16(src, dst);
  }
}

// ---------------- fused preprocess: weight cvt (bid<40960), rope table (<41472), fq(hs) (rest) ----------------
__global__ __launch_bounds__(256) void preproc_k(const float* __restrict__ Wq, const float* __restrict__ Wk,
                                                 const float* __restrict__ Wv, const float* __restrict__ Wo,
                                                 bf16* __restrict__ qkvW, bf16* __restrict__ WoB,
                                                 const int* __restrict__ pos, float* __restrict__ cosT,
                                                 float* __restrict__ sinT,
                                                 const float* __restrict__ h, const float* __restrict__ qb1,
                                                 bf16* __restrict__ hs){
  __shared__ float red[4];
  int bid = blockIdx.x;
  int tid = threadIdx.x;
  if (bid < 40960){
    int i = bid * 256 + tid;   // float4 units
    const float4* src; bf16* dstb; int j;
    if (i < 4194304){ src = (const float4*)Wq; dstb = qkvW; j = i; }
    else if (i < 5242880){ src = (const float4*)Wk; dstb = qkvW + (size_t)16777216; j = i - 4194304; }
    else if (i < 6291456){ src = (const float4*)Wv; dstb = qkvW + (size_t)20971520; j = i - 5242880; }
    else { src = (const float4*)Wo; dstb = WoB; j = i - 6291456; }
    float4 v = src[j];
    bf16x4 o = { (bf16)v.x, (bf16)v.y, (bf16)v.z, (bf16)v.w };
    ((bf16x4*)dstb)[j] = o;
  } else if (bid < 41472){
    int idx = (bid - 40960) * 256 + tid;
    int t = idx >> 6, j = idx & 63;
    float inv = powf(10000.f, -(float)j * (1.f/64.f));
    float f = (float)pos[t] * inv;
    cosT[idx] = cosf(f);
    sinT[idx] = sinf(f);
  } else {
    int t = bid - 41472;
    const float4* row = (const float4*)(h + (size_t)t * HID);
    const float4* qb4 = (const float4*)qb1;
    float4 x[4], b[4];
    float amax = 0.f;
    #pragma unroll
    for (int i = 0; i < 4; i++){
      int c4 = tid + i * 256;
      float4 v = row[c4];
      float4 bb = qb4[c4];
      v.x -= bb.x; v.y -= bb.y; v.z -= bb.z; v.w -= bb.w;
      x[i] = v; b[i] = bb;
      amax = fmaxf(amax, fmaxf(fmaxf(fabsf(v.x), fabsf(v.y)), fmaxf(fabsf(v.z), fabsf(v.w))));
    }
    #pragma unroll
    for (int d = 1; d < 64; d <<= 1) amax = fmaxf(amax, __shfl_xor(amax, d));
    if ((tid & 63) == 0) red[tid >> 6] = amax;
    __syncthreads();
    amax = fmaxf(fmaxf(red[0], red[1]), fmaxf(red[2], red[3]));
    float s = fmaxf(amax, 1e-8f) / 127.f;
    bf16x4* ob = (bf16x4*)(hs + (size_t)t * HID);
    #pragma unroll
    for (int i = 0; i < 4; i++){
      int c4 = tid + i * 256;
      bf16x4 o = { (bf16)(fq_round(x[i].x, s) + b[i].x),
                   (bf16)(fq_round(x[i].y, s) + b[i].y),
                   (bf16)(fq_round(x[i].z, s) + b[i].z),
                   (bf16)(fq_round(x[i].w, s) + b[i].w) };
      ob[c4] = o;
    }
  }
}

// ---------------- 128x192 bf16 GEMM (QKV), 2 blocks/CU, wave 64x96 ----------------
__global__ __launch_bounds__(256, 2) void gemm9(const bf16* __restrict__ A, const bf16* __restrict__ B,
                                                float* __restrict__ C, int N, int K){
  __shared__ bf16 As[2][128 * 64];
  __shared__ bf16 Bs[2][192 * 64];
  int orig = blockIdx.y * gridDim.x + blockIdx.x;   // 0..511
  int nid = (orig & 7) * 64 + (orig >> 3);          // XCD-contiguous, bijective (512%8==0)
  int bm = (nid >> 5) * 128, bn = (nid & 31) * 192;
  int tid = threadIdx.x, lane = tid & 63, wid = tid >> 6;
  int wr = wid >> 1, wc = wid & 1;
  int lq = lane & 15, lg = lane >> 4;
  f32x4 acc[4][6] = {};
  int nk = K >> 6;

  const bf16* Abase = A + (size_t)bm * K;
  const bf16* Bbase = B + (size_t)bn * K;
  size_t rowb = (size_t)K * 2;

  auto stage_a = [&](bf16* lds, int t){
    const char* g0 = (const char*)Abase + (size_t)t * 128;
    #pragma unroll
    for (int i = 0; i < 4; i++){
      int f = i * 256 + tid;
      int r = f >> 3, g = f & 7;
      gload_lds16(g0 + (size_t)r * rowb + (size_t)((g ^ (r & 7)) << 4),
                  (char*)lds + (size_t)f * 16);
    }
  };
  auto stage_b = [&](bf16* lds, int t){
    const char* g0 = (const char*)Bbase + (size_t)t * 128;
    #pragma unroll
    for (int i = 0; i < 6; i++){
      int f = i * 256 + tid;
      int r = f >> 3, g = f & 7;
      gload_lds16(g0 + (size_t)r * rowb + (size_t)((g ^ (r & 7)) << 4),
                  (char*)lds + (size_t)f * 16);
    }
  };

  stage_a(As[0], 0);
  stage_b(Bs[0], 0);

  for (int t = 0; t < nk; t++){
    if (t + 1 < nk){
      stage_a(As[(t + 1) & 1], t + 1);
      stage_b(Bs[(t + 1) & 1], t + 1);
      asm volatile("s_waitcnt vmcnt(10)" ::: "memory");
    } else {
      asm volatile("s_waitcnt vmcnt(0)" ::: "memory");
    }
    __builtin_amdgcn_s_barrier();
    const bf16* at = As[t & 1];
    const bf16* bt = Bs[t & 1];

    #pragma unroll
    for (int ks = 0; ks < 2; ks++){
      int gg = ks * 4 + lg;
      bf16x8 bfr[6];
      #pragma unroll
      for (int nf = 0; nf < 6; nf++){
        int rr = wc * 96 + nf * 16 + lq;
        bfr[nf] = *(const bf16x8*)(bt + rr * 64 + ((gg ^ (rr & 7)) << 3));
      }
      bf16x8 af[4];
      #pragma unroll
      for (int mf = 0; mf < 4; mf++){
        int rr = wr * 64 + mf * 16 + lq;
        af[mf] = *(const bf16x8*)(at + rr * 64 + ((gg ^ (rr & 7)) << 3));
      }
      __builtin_amdgcn_s_setprio(1);
      #pragma unroll
      for (int mf = 0; mf < 4; mf++)
        #pragma unroll
        for (int nf = 0; nf < 6; nf++)
          acc[mf][nf] = __builtin_amdgcn_mfma_f32_16x16x32_bf16(af[mf], bfr[nf], acc[mf][nf], 0, 0, 0);
      __builtin_amdgcn_s_setprio(0);
    }
    __builtin_amdgcn_s_barrier();
  }

  #pragma unroll
  for (int mf = 0; mf < 4; mf++){
    int mrow = bm + wr * 64 + mf * 16 + 4 * lg;
    #pragma unroll
    for (int nf = 0; nf < 6; nf++){
      int ncol = bn + wc * 96 + nf * 16 + lq;
      #pragma unroll
      for (int i = 0; i < 4; i++)
        C[(size_t)(mrow + i) * N + ncol] = acc[mf][nf][i];
    }
  }
}

// ---------------- bf16 GEMM: A[2048,K] x B[N,K]^T -> C[2048,N], BK=64, dbuf + counted vmcnt ----------------
__global__ __launch_bounds__(256, 2) void gemm_bt(const bf16* __restrict__ A, const bf16* __restrict__ B,
                                                  float* __restrict__ C, int N, int K){
  __shared__ bf16 As[2][128 * 64];
  __shared__ bf16 Bs[2][128 * 64];
  int bm = blockIdx.y * 128, bn = blockIdx.x * 128;
  int tid = threadIdx.x, wid = tid >> 6, lane = tid & 63;
  int wr = wid >> 1, wc = wid & 1;
  f32x4 acc[4][4] = {};
  int nk = K >> 6;
  stage_g8(A + (size_t)bm * K, (size_t)K * 2, As[0], tid);
  stage_g8(B + (size_t)bn * K, (size_t)K * 2, Bs[0], tid);
  for (int t = 0; t < nk; t++){
    if (t + 1 < nk){
      stage_g8(A + (size_t)bm * K + (t + 1) * 64, (size_t)K * 2, As[(t + 1) & 1], tid);
      stage_g8(B + (size_t)bn * K + (t + 1) * 64, (size_t)K * 2, Bs[(t + 1) & 1], tid);
      asm volatile("s_waitcnt vmcnt(8)" ::: "memory");
    } else {
      asm volatile("s_waitcnt vmcnt(0)" ::: "memory");
    }
    __builtin_amdgcn_s_barrier();
    const bf16* at = As[t & 1];
    const bf16* bt = Bs[t & 1];
    __builtin_amdgcn_s_setprio(1);
    #pragma unroll
    for (int ks2 = 0; ks2 < 2; ks2++){
      bf16x8 af[4], bfr[4];
      int g = ks2 * 4 + (lane >> 4);
      #pragma unroll
      for (int mf = 0; mf < 4; mf++){
        int rr = wr * 64 + mf * 16 + (lane & 15);
        af[mf] = *(const bf16x8*)(at + rr * 64 + ((g ^ (rr & 7)) << 3));
      }
      #pragma unroll
      for (int nf = 0; nf < 4; nf++){
        int rr = wc * 64 + nf * 16 + (lane & 15);
        bfr[nf] = *(const bf16x8*)(bt + rr * 64 + ((g ^ (rr & 7)) << 3));
      }
      #pragma unroll
      for (int mf = 0; mf < 4; mf++)
        #pragma unroll
        for (int nf = 0; nf < 4; nf++)
          acc[mf][nf] = __builtin_amdgcn_mfma_f32_16x16x32_bf16(af[mf], bfr[nf], acc[mf][nf], 0, 0, 0);
    }
    __builtin_amdgcn_s_setprio(0);
    __builtin_amdgcn_s_barrier();
  }
  int mrow = bm + wr * 64 + 4 * (lane >> 4);
  int ncol = bn + wc * 64 + (lane & 15);
  #pragma unroll
  for (int mf = 0; mf < 4; mf++)
    #pragma unroll
    for (int nf = 0; nf < 4; nf++)
      #pragma unroll
      for (int i = 0; i < 4; i++)
        C[(size_t)(mrow + mf * 16 + i) * N + ncol + nf * 16] = acc[mf][nf][i];
}

// ---------------- fused rope: Q (fq->f16), K (fp32), and V per-channel absmax ----------------
__global__ __launch_bounds__(256) void rope_qk_k(const float* __restrict__ qkvraw, const float* __restrict__ cosT,
                                                 const float* __restrict__ sinT, f16* __restrict__ qf,
                                                 float* __restrict__ krope, float* __restrict__ vamax){
  int bid = blockIdx.x;
  int lane = threadIdx.x & 63;
  if (bid < 16384){
    int row = bid * 4 + (threadIdx.x >> 6);
    int hh = row >> 11, t = row & 2047;
    const float* qp = qkvraw + (size_t)t * NQKV + hh * HD;
    float q1 = qp[lane], q2 = qp[lane + 64];
    float c = cosT[t * 64 + lane], s = sinT[t * 64 + lane];
    float r1 = q1 * c - q2 * s;
    float r2 = q2 * c + q1 * s;
    float amax = fmaxf(fabsf(r1), fabsf(r2));
    #pragma unroll
    for (int d = 1; d < 64; d <<= 1) amax = fmaxf(amax, __shfl_xor(amax, d));
    float sc = fmaxf(amax, 1e-8f) / 127.f;
    const float kq = 0.08838834764831845f;
    f16* o = qf + ((size_t)hh * SEQ + t) * HD;
    o[lane]      = (f16)(fq_round(r1, sc) * kq);
    o[lane + 64] = (f16)(fq_round(r2, sc) * kq);
  } else if (bid < 20480){
    int row = (bid - 16384) * 4 + (threadIdx.x >> 6);
    int kvh = row >> 11, t = row & 2047;
    const float* kp = qkvraw + (size_t)t * NQKV + 4096 + kvh * HD;
    float k1 = kp[lane], k2 = kp[lane + 64];
    float c = cosT[t * 64 + lane], s = sinT[t * 64 + lane];
    float* o = krope + ((size_t)kvh * SEQ + t) * HD;
    o[lane]      = k1 * c - k2 * s;
    o[lane + 64] = k2 * c + k1 * s;
  } else {
    // V per-channel absmax: 64 blocks x 32 rows, coalesced float4
    int slice = bid - 20480;
    int tid = threadIdx.x;
    const float4* p = (const float4*)qkvraw;
    float a0 = 0.f, a1 = 0.f, a2 = 0.f, a3 = 0.f;
    for (int r = 0; r < 32; r++){
      float4 v = p[(size_t)(slice * 32 + r) * 1536 + 1280 + tid];
      a0 = fmaxf(a0, fabsf(v.x)); a1 = fmaxf(a1, fabsf(v.y));
      a2 = fmaxf(a2, fabsf(v.z)); a3 = fmaxf(a3, fabsf(v.w));
    }
    atomicMax((int*)&vamax[tid * 4 + 0], __float_as_int(a0));
    atomicMax((int*)&vamax[tid * 4 + 1], __float_as_int(a1));
    atomicMax((int*)&vamax[tid * 4 + 2], __float_as_int(a2));
    atomicMax((int*)&vamax[tid * 4 + 3], __float_as_int(a3));
  }
}

// ---------------- per-channel absmax for K (rope'd) ----------------
__global__ __launch_bounds__(256) void kmax_k(const float* __restrict__ krope, float* __restrict__ kamax){
  int bid = blockIdx.x;
  int tid = threadIdx.x;
  int kvh = bid >> 3, slice = bid & 7;
  int c = tid & 127, rh = tid >> 7;
  const float* p = krope + ((size_t)kvh * SEQ + slice * 256 + rh) * HD + c;
  float a = 0.f;
  #pragma unroll 8
  for (int r = 0; r < 128; r++) a = fmaxf(a, fabsf(p[(size_t)r * 2 * HD]));
  atomicMax((int*)&kamax[kvh * 128 + c], __float_as_int(a));
}

// ---------------- fused quantize: K -> f16 [kvh][t][d]; V -> f16 transposed [kvh][d][t] ----------------
__global__ __launch_bounds__(256) void quant_kv_k(const float* __restrict__ krope, const float* __restrict__ qkvraw,
                                                  const float* __restrict__ kamax, const float* __restrict__ vamax,
                                                  f16* __restrict__ kf, f16* __restrict__ vt){
  __shared__ float tile[64][65];
  int bid = blockIdx.x;
  if (bid < 8192){
    int idx = bid * 256 + threadIdx.x;
    int d = idx & 127;
    int h = idx >> 18;
    float s = fmaxf(kamax[(h << 7) + d], 1e-8f) / 127.f;
    kf[idx] = (f16)fq_round(krope[idx], s);
  } else {
    int vid = bid - 8192;            // 0..511
    int t0 = (vid & 31) * 64;
    int c0 = (vid >> 5) * 64;
    int tx = threadIdx.x & 63, ty = threadIdx.x >> 6;
    #pragma unroll
    for (int i = 0; i < 16; i++){
      int r = i * 4 + ty;
      tile[r][tx] = qkvraw[(size_t)(t0 + r) * NQKV + 5120 + c0 + tx];
    }
    __syncthreads();
    #pragma unroll
    for (int i = 0; i < 16; i++){
      int dch = i * 4 + ty;
      int ch = c0 + dch;
      float s = fmaxf(vamax[ch], 1e-8f) / 127.f;
      vt[(size_t)ch * SEQ + t0 + tx] = (f16)fq_round(tile[tx][dch], s);
    }
  }
}

// ---------------- attention: swapped QK^T + staged LDS; wave-uniform mask paths; e'=exp(s-m+ln127) ----------------
__global__ __launch_bounds__(256, 2) void attn_k(const f16* __restrict__ qf, const f16* __restrict__ kf,
                                                 const f16* __restrict__ vt, float* __restrict__ aout){
  int pr = blockIdx.x;            // 0..15
  int hh = blockIdx.y;            // 0..31
  int qtA = pr, qtB = 31 - pr;
  int kvh = hh >> 2;
  int tid = threadIdx.x, wid = tid >> 6, lane = tid & 63;
  int lq = lane & 15, lg = lane >> 4;

  __shared__ f16 ks[2][64 * 128];
  __shared__ f16 vs[2][128 * 64];
  __shared__ f16 ps[4][16][80];

  f16x8 bqA[4], bqB[4];
  {
    const f16* qbA = qf + ((size_t)hh * SEQ + qtA * 64 + wid * 16 + lq) * HD + lg * 8;
    const f16* qbB = qf + ((size_t)hh * SEQ + qtB * 64 + wid * 16 + lq) * HD + lg * 8;
    #pragma unroll
    for (int kk = 0; kk < 4; kk++){
      bqA[kk] = *(const f16x8*)(qbA + kk * 32);
      bqB[kk] = *(const f16x8*)(qbB + kk * 32);
    }
  }
  int qgA = qtA * 64 + wid * 16 + lq;
  int qgB = qtB * 64 + wid * 16 + lq;

  const f16* kbase = kf + (size_t)kvh * SEQ * HD;
  const f16* vbase = vt + (size_t)kvh * HD * SEQ;
  int nkb = qtB + 1;

  // ---- pass 1: exact per-row max (unmasked fast path off-diagonal) ----
  float mxA = -1e30f, mxB = -1e30f;
  stage_g16(kbase, (size_t)HD * 2, ks[0], tid);
  for (int kb = 0; kb < nkb; kb++){
    if (kb + 1 < nkb){
      stage_g16(kbase + (size_t)(kb + 1) * 64 * HD, (size_t)HD * 2, ks[(kb + 1) & 1], tid);
      asm volatile("s_waitcnt vmcnt(4)" ::: "memory");
    } else {
      asm volatile("s_waitcnt vmcnt(0)" ::: "memory");
    }
    __builtin_amdgcn_s_barrier();
    const f16* kt = ks[kb & 1];
    bool doA = (kb <= qtA);
    bool diagB = (kb == qtB), diagA = (kb == qtA);
    __builtin_amdgcn_s_setprio(1);
    #pragma unroll
    for (int nf = 0; nf < 4; nf++){
      int rr = nf * 16 + lq;
      f16x8 ka[4];
      #pragma unroll
      for (int kk = 0; kk < 4; kk++)
        ka[kk] = *(const f16x8*)(kt + rr * 128 + (((kk * 4 + lg) ^ (rr & 15)) << 3));
      int k0 = kb * 64 + nf * 16 + lg * 4;
      f32x4 sB = {0.f, 0.f, 0.f, 0.f};
      #pragma unroll
      for (int kk = 0; kk < 4; kk++) sB = __builtin_amdgcn_mfma_f32_16x16x32_f16(ka[kk], bqB[kk], sB, 0, 0, 0);
      if (!diagB){
        #pragma unroll
        for (int i = 0; i < 4; i++) mxB = fmaxf(mxB, sB[i]);
      } else {
        #pragma unroll
        for (int i = 0; i < 4; i++)
          if (k0 + i <= qgB) mxB = fmaxf(mxB, sB[i]);
      }
      if (doA){
        f32x4 sA = {0.f, 0.f, 0.f, 0.f};
        #pragma unroll
        for (int kk = 0; kk < 4; kk++) sA = __builtin_amdgcn_mfma_f32_16x16x32_f16(ka[kk], bqA[kk], sA, 0, 0, 0);
        if (!diagA){
          #pragma unroll
          for (int i = 0; i < 4; i++) mxA = fmaxf(mxA, sA[i]);
        } else {
          #pragma unroll
          for (int i = 0; i < 4; i++)
            if (k0 + i <= qgA) mxA = fmaxf(mxA, sA[i]);
        }
      }
    }
    __builtin_amdgcn_s_setprio(0);
    __builtin_amdgcn_s_barrier();
  }
  mxB = fmaxf(mxB, __shfl_xor(mxB, 16)); mxB = fmaxf(mxB, __shfl_xor(mxB, 32));
  mxA = fmaxf(mxA, __shfl_xor(mxA, 16)); mxA = fmaxf(mxA, __shfl_xor(mxA, 32));
  float mB2 = mxB - LN127;   // e' = exp(s - mB2) = 127*exp(s - m)
  float mA2 = mxA - LN127;

  // ---- pass 2: integer P = rint(e'), l' = sum e' (=127 l), PV ----
  float lsA = 0.f, lsB = 0.f;
  f32x4 oA[8] = {}, oB[8] = {};
  stage_g16(kbase, (size_t)HD * 2, ks[0], tid);
  stage_g8(vbase, (size_t)SEQ * 2, vs[0], tid);
  for (int kb = 0; kb < nkb; kb++){
    if (kb + 1 < nkb){
      stage_g16(kbase + (size_t)(kb + 1) * 64 * HD, (size_t)HD * 2, ks[(kb + 1) & 1], tid);
      stage_g8(vbase + (kb + 1) * 64, (size_t)SEQ * 2, vs[(kb + 1) & 1], tid);
      asm volatile("s_waitcnt vmcnt(8)" ::: "memory");
    } else {
      asm volatile("s_waitcnt vmcnt(0)" ::: "memory");
    }
    __builtin_amdgcn_s_barrier();
    const f16* kt = ks[kb & 1];
    const f16* vtile = vs[kb & 1];
    bool doA = (kb <= qtA);
    bool diagB = (kb == qtB), diagA = (kb == qtA);
    f32x4 saccA[4];

    __builtin_amdgcn_s_setprio(1);
    #pragma unroll
    for (int nf = 0; nf < 4; nf++){
      int rr = nf * 16 + lq;
      f16x8 ka[4];
      #pragma unroll
      for (int kk = 0; kk < 4; kk++)
        ka[kk] = *(const f16x8*)(kt + rr * 128 + (((kk * 4 + lg) ^ (rr & 15)) << 3));
      f32x4 sB = {0.f, 0.f, 0.f, 0.f};
      #pragma unroll
      for (int kk = 0; kk < 4; kk++) sB = __builtin_amdgcn_mfma_f32_16x16x32_f16(ka[kk], bqB[kk], sB, 0, 0, 0);
      if (doA){
        f32x4 sA = {0.f, 0.f, 0.f, 0.f};
        #pragma unroll
        for (int kk = 0; kk < 4; kk++) sA = __builtin_amdgcn_mfma_f32_16x16x32_f16(ka[kk], bqA[kk], sA, 0, 0, 0);
        saccA[nf] = sA;
      }
      int k0 = kb * 64 + nf * 16 + lg * 4;
      f16x4 pB4;
      if (!diagB){
        #pragma unroll
        for (int i = 0; i < 4; i++){
          float e = __expf(sB[i] - mB2);
          lsB += e;
          pB4[i] = (f16)rintf(e);
        }
      } else {
        #pragma unroll
        for (int i = 0; i < 4; i++){
          float e = (k0 + i <= qgB) ? __expf(sB[i] - mB2) : 0.f;
          lsB += e;
          pB4[i] = (f16)rintf(e);
        }
      }
      *(f16x4*)&ps[wid][lq][nf * 16 + lg * 4] = pB4;
    }
    {
      f16x8 pa0 = *(const f16x8*)&ps[wid][lq][lg * 8];
      f16x8 pa1 = *(const f16x8*)&ps[wid][lq][32 + lg * 8];
      #pragma unroll
      for (int nf2 = 0; nf2 < 8; nf2++){
        int rr = nf2 * 16 + lq;
        f16x8 v0 = *(const f16x8*)(vtile + rr * 64 + (((lg) ^ (rr & 7)) << 3));
        f16x8 v1 = *(const f16x8*)(vtile + rr * 64 + (((4 + lg) ^ (rr & 7)) << 3));
        oB[nf2] = __builtin_amdgcn_mfma_f32_16x16x32_f16(pa0, v0, oB[nf2], 0, 0, 0);
        oB[nf2] = __builtin_amdgcn_mfma_f32_16x16x32_f16(pa1, v1, oB[nf2], 0, 0, 0);
      }
    }
    if (doA){
      #pragma unroll
      for (int nf = 0; nf < 4; nf++){
        int k0 = kb * 64 + nf * 16 + lg * 4;
        f16x4 pA4;
        if (!diagA){
          #pragma unroll
          for (int i = 0; i < 4; i++){
            float e = __expf(saccA[nf][i] - mA2);
            lsA += e;
            pA4[i] = (f16)rintf(e);
          }
        } else {
          #pragma unroll
          for (int i = 0; i < 4; i++){
            float e = (k0 + i <= qgA) ? __expf(saccA[nf][i] - mA2) : 0.f;
            lsA += e;
            pA4[i] = (f16)rintf(e);
          }
        }
        *(f16x4*)&ps[wid][lq][nf * 16 + lg * 4] = pA4;
      }
      f16x8 pa0 = *(const f16x8*)&ps[wid][lq][lg * 8];
      f16x8 pa1 = *(const f16x8*)&ps[wid][lq][32 + lg * 8];
      #pragma unroll
      for (int nf2 = 0; nf2 < 8; nf2++){
        int rr = nf2 * 16 + lq;
        f16x8 v0 = *(const f16x8*)(vtile + rr * 64 + (((lg) ^ (rr & 7)) << 3));
        f16x8 v1 = *(const f16x8*)(vtile + rr * 64 + (((4 + lg) ^ (rr & 7)) << 3));
        oA[nf2] = __builtin_amdgcn_mfma_f32_16x16x32_f16(pa0, v0, oA[nf2], 0, 0, 0);
        oA[nf2] = __builtin_amdgcn_mfma_f32_16x16x32_f16(pa1, v1, oA[nf2], 0, 0, 0);
      }
    }
    __builtin_amdgcn_s_setprio(0);
    __builtin_amdgcn_s_barrier();
  }

  lsB += __shfl_xor(lsB, 16); lsB += __shfl_xor(lsB, 32);
  lsA += __shfl_xor(lsA, 16); lsA += __shfl_xor(lsA, 32);

  // epilogue: scale = 1/l' (= 1/(127 l)); per-row fq over HD
  auto epilogue = [&](f32x4* oacc, float lrow, int qt){
    float inv[4];
    #pragma unroll
    for (int i = 0; i < 4; i++)
      inv[i] = 1.f / __shfl(lrow, lg * 4 + i);
    float am[4] = {0.f, 0.f, 0.f, 0.f};
    #pragma unroll
    for (int nf2 = 0; nf2 < 8; nf2++)
      #pragma unroll
      for (int i = 0; i < 4; i++)
        am[i] = fmaxf(am[i], fabsf(oacc[nf2][i] * inv[i]));
    #pragma unroll
    for (int i = 0; i < 4; i++){
      float a = am[i];
      #pragma unroll
      for (int d = 1; d < 16; d <<= 1) a = fmaxf(a, __shfl_xor(a, d));
      am[i] = a;
    }
    #pragma unroll
    for (int i = 0; i < 4; i++){
      float so = fmaxf(am[i], 1e-8f) / 127.f;
      int row = qt * 64 + wid * 16 + lg * 4 + i;
      float* op = aout + ((size_t)hh * SEQ + row) * HD + lq;
      #pragma unroll
      for (int nf2 = 0; nf2 < 8; nf2++){
        float v = oacc[nf2][i] * inv[i];
        op[nf2 * 16] = fq_round(v, so);
      }
    }
  };
  epilogue(oB, lsB, qtB);
  epilogue(oA, lsA, qtA);
}

// ---------------- epilogue: gather heads, *o_scale2, fq(out - qb2) + qb2 -> bf16 (float4) ----------------
__global__ __launch_bounds__(256) void epi_k(const float* __restrict__ aout, const float* __restrict__ osc,
                                             const float* __restrict__ qb2, bf16* __restrict__ act){
  int t = blockIdx.x, tid = threadIdx.x;
  const float4* osc4 = (const float4*)osc;
  const float4* qb4  = (const float4*)qb2;
  float4 z[4]; float amax = 0.f;
  #pragma unroll
  for (int i = 0; i < 4; i++){
    int o4 = tid + i * 256;          // float4 index; elems o4*4..o4*4+3 (same head block)
    int o = o4 * 4;
    int h = o >> 7, d = o & 127;
    float4 y = *(const float4*)(aout + ((size_t)h * SEQ + t) * HD + d);
    float4 sc = osc4[o4], bb = qb4[o4];
    float4 zz = { y.x * sc.x - bb.x, y.y * sc.y - bb.y, y.z * sc.z - bb.z, y.w * sc.w - bb.w };
    z[i] = zz;
    amax = fmaxf(amax, fmaxf(fmaxf(fabsf(zz.x), fabsf(zz.y)), fmaxf(fabsf(zz.z), fabsf(zz.w))));
  }
  #pragma unroll
  for (int d = 1; d < 64; d <<= 1) amax = fmaxf(amax, __shfl_xor(amax, d));
  __shared__ float red[4];
  if ((tid & 63) == 0) red[tid >> 6] = amax;
  __syncthreads();
  amax = fmaxf(fmaxf(red[0], red[1]), fmaxf(red[2], red[3]));
  float s = fmaxf(amax, 1e-8f) / 127.f;
  bf16x4* ab = (bf16x4*)(act + (size_t)t * HID);
  #pragma unroll
  for (int i = 0; i < 4; i++){
    int o4 = tid + i * 256;
    float4 bb = qb4[o4];
    bf16x4 o = { (bf16)(fq_round(z[i].x, s) + bb.x),
                 (bf16)(fq_round(z[i].y, s) + bb.y),
                 (bf16)(fq_round(z[i].z, s) + bb.z),
                 (bf16)(fq_round(z[i].w, s) + bb.w) };
    ab[o4] = o;
  }
}

extern "C" void kernel_launch(void* const* d_in, const int* in_sizes, int n_in,
                              void* d_out, int out_size, void* d_ws, size_t ws_size,
                              hipStream_t stream) {
  const float* hidden = (const float*)d_in[0];
  const int*   pos    = (const int*)d_in[1];
  const float* Wq     = (const float*)d_in[2];
  const float* Wk     = (const float*)d_in[3];
  const float* Wv     = (const float*)d_in[4];
  const float* Wo     = (const float*)d_in[5];
  const float* qb1    = (const float*)d_in[6];
  const float* qb2    = (const float*)d_in[7];
  const float* osc    = (const float*)d_in[8];
  float* out = (float*)d_out;

  char* w = (char*)d_ws;
  size_t off = 0;
  auto take = [&](size_t b) -> char* {
    char* p = w + off;
    off += (b + 255) & ~(size_t)255;
    return p;
  };
  bf16* qkvW  = (bf16*)take((size_t)NQKV * HID * 2);     // [6144][4096]
  bf16* WoB   = (bf16*)take((size_t)HID * HID * 2);
  bf16* hsB   = (bf16*)take((size_t)SEQ * HID * 2);
  float* cosT = (float*)take((size_t)SEQ * 64 * 4);
  float* sinT = (float*)take((size_t)SEQ * 64 * 4);
  float* qkv_raw = (float*)take((size_t)SEQ * NQKV * 4); // [2048][6144]
  float* krope = (float*)take((size_t)NKV * SEQ * HD * 4);
  f16* qf  = (f16*)take((size_t)NH * SEQ * HD * 2);
  f16* kf  = (f16*)take((size_t)NKV * SEQ * HD * 2);
  f16* vtf = (f16*)take((size_t)NKV * HD * SEQ * 2);
  float* kvamax = (float*)take(2048 * 4);
  float* kamax = kvamax, *vamax = kvamax + 1024;
  float* aout = qkv_raw;   // alias: qkv_raw dead after rope/quant kernels
  bf16*  act  = hsB;       // alias: hs dead after QKV GEMM

  hipMemsetAsync(kvamax, 0, 2048 * sizeof(float), stream);
  preproc_k<<<43520, 256, 0, stream>>>(Wq, Wk, Wv, Wo, qkvW, WoB, pos, cosT, sinT, hidden, qb1, hsB);
  gemm9<<<dim3(32, 16), 256, 0, stream>>>(hsB, qkvW, qkv_raw, NQKV, 4096);
  rope_qk_k<<<20544, 256, 0, stream>>>(qkv_raw, cosT, sinT, qf, krope, vamax);
  kmax_k<<<64, 256, 0, stream>>>(krope, kamax);
  quant_kv_k<<<8704, 256, 0, stream>>>(krope, qkv_raw, kamax, vamax, kf, vtf);
  attn_k<<<dim3(16, 32), 256, 0, stream>>>(qf, kf, vtf, aout);
  epi_k<<<2048, 256, 0, stream>>>(aout, osc, qb2, act);
  gemm_bt<<<dim3(32, 16), 256, 0, stream>>>(act, WoB, out, 4096, 4096);
}

// Round 20
// 385.899 us; speedup vs baseline: 1.0169x; 1.0169x over previous
//
#include <hip/hip_runtime.h>
#include <stdint.h>

typedef _Float16 f16;
typedef __bf16 bf16;
typedef f16 f16x4 __attribute__((ext_vector_type(4)));
typedef f16 f16x8 __attribute__((ext_vector_type(8)));
typedef bf16 bf16x4 __attribute__((ext_vector_type(4)));
typedef bf16 bf16x8 __attribute__((ext_vector_type(8)));
typedef float f32x4 __attribute__((ext_vector_type(4)));

#define SEQ 2048
#define HID 4096
#define NH 32
#define NKV 8
#define HD 128
#define NQKV 6144
#define LN127 4.8441870864585870f

__device__ __forceinline__ float fq_round(float x, float s){
  float r = rintf(x / s);
  r = fminf(fmaxf(r, -128.f), 127.f);
  return r * s;
}

__device__ __forceinline__ void gload_lds16(const void* g, void* l){
  __builtin_amdgcn_global_load_lds(
      (const __attribute__((address_space(1))) uint32_t*)g,
      (__attribute__((address_space(3))) uint32_t*)l, 16, 0, 0);
}

// stage a [128 rows][8 granules-of-16B] tile (row = 64 f16/bf16), XOR-swizzled. 256 thr, 4 loads/thread.
__device__ __forceinline__ void stage_g8(const void* gbase, size_t row_bytes, void* lds, int tid){
  int w = tid >> 6, l = tid & 63;
  #pragma unroll
  for (int i = 0; i < 4; i++){
    int flat = i * 256 + w * 64 + l;
    int r = flat >> 3, g = flat & 7;
    const char* src = (const char*)gbase + (size_t)r * row_bytes + (size_t)((g ^ (r & 7)) << 4);
    char* dst = (char*)lds + (size_t)(i * 256 + w * 64) * 16;
    gload_lds16(src, dst);
  }
}
// stage a [64 rows][16 granules-of-16B] tile (row = 128 f16), XOR-swizzled. 256 thr, 4 loads/thread.
__device__ __forceinline__ void stage_g16(const void* gbase, size_t row_bytes, void* lds, int tid){
  int w = tid >> 6, l = tid & 63;
  #pragma unroll
  for (int i = 0; i < 4; i++){
    int flat = i * 256 + w * 64 + l;
    int r = flat >> 4, g = flat & 15;
    const char* src = (const char*)gbase + (size_t)r * row_bytes + (size_t)((g ^ (r & 15)) << 4);
    char* dst = (char*)lds + (size_t)(i * 256 + w * 64) * 16;
    gload_lds16(src, dst);
  }
}

// ---------------- fused preprocess: weight cvt (bid<40960), rope table (<41472), fq(hs) (rest) ----------------
__global__ __launch_bounds__(256) void preproc_k(const float* __restrict__ Wq, const float* __restrict__ Wk,
                                                 const float* __restrict__ Wv, const float* __restrict__ Wo,
                                                 bf16* __restrict__ qkvW, bf16* __restrict__ WoB,
                                                 const int* __restrict__ pos, float* __restrict__ cosT,
                                                 float* __restrict__ sinT,
                                                 const float* __restrict__ h, const float* __restrict__ qb1,
                                                 bf16* __restrict__ hs){
  __shared__ float red[4];
  int bid = blockIdx.x;
  int tid = threadIdx.x;
  if (bid < 40960){
    int i = bid * 256 + tid;   // float4 units
    const float4* src; bf16* dstb; int j;
    if (i < 4194304){ src = (const float4*)Wq; dstb = qkvW; j = i; }
    else if (i < 5242880){ src = (const float4*)Wk; dstb = qkvW + (size_t)16777216; j = i - 4194304; }
    else if (i < 6291456){ src = (const float4*)Wv; dstb = qkvW + (size_t)20971520; j = i - 5242880; }
    else { src = (const float4*)Wo; dstb = WoB; j = i - 6291456; }
    float4 v = src[j];
    bf16x4 o = { (bf16)v.x, (bf16)v.y, (bf16)v.z, (bf16)v.w };
    ((bf16x4*)dstb)[j] = o;
  } else if (bid < 41472){
    int idx = (bid - 40960) * 256 + tid;
    int t = idx >> 6, j = idx & 63;
    float inv = powf(10000.f, -(float)j * (1.f/64.f));
    float f = (float)pos[t] * inv;
    cosT[idx] = cosf(f);
    sinT[idx] = sinf(f);
  } else {
    int t = bid - 41472;
    const float4* row = (const float4*)(h + (size_t)t * HID);
    const float4* qb4 = (const float4*)qb1;
    float4 x[4], b[4];
    float amax = 0.f;
    #pragma unroll
    for (int i = 0; i < 4; i++){
      int c4 = tid + i * 256;
      float4 v = row[c4];
      float4 bb = qb4[c4];
      v.x -= bb.x; v.y -= bb.y; v.z -= bb.z; v.w -= bb.w;
      x[i] = v; b[i] = bb;
      amax = fmaxf(amax, fmaxf(fmaxf(fabsf(v.x), fabsf(v.y)), fmaxf(fabsf(v.z), fabsf(v.w))));
    }
    #pragma unroll
    for (int d = 1; d < 64; d <<= 1) amax = fmaxf(amax, __shfl_xor(amax, d));
    if ((tid & 63) == 0) red[tid >> 6] = amax;
    __syncthreads();
    amax = fmaxf(fmaxf(red[0], red[1]), fmaxf(red[2], red[3]));
    float s = fmaxf(amax, 1e-8f) / 127.f;
    bf16x4* ob = (bf16x4*)(hs + (size_t)t * HID);
    #pragma unroll
    for (int i = 0; i < 4; i++){
      int c4 = tid + i * 256;
      bf16x4 o = { (bf16)(fq_round(x[i].x, s) + b[i].x),
                   (bf16)(fq_round(x[i].y, s) + b[i].y),
                   (bf16)(fq_round(x[i].z, s) + b[i].z),
                   (bf16)(fq_round(x[i].w, s) + b[i].w) };
      ob[c4] = o;
    }
  }
}

// ---------------- 128x192 bf16 GEMM (QKV), 2 blocks/CU, wave 64x96 ----------------
__global__ __launch_bounds__(256, 2) void gemm9(const bf16* __restrict__ A, const bf16* __restrict__ B,
                                                float* __restrict__ C, int N, int K){
  __shared__ bf16 As[2][128 * 64];
  __shared__ bf16 Bs[2][192 * 64];
  int orig = blockIdx.y * gridDim.x + blockIdx.x;   // 0..511
  int nid = (orig & 7) * 64 + (orig >> 3);          // XCD-contiguous, bijective (512%8==0)
  int bm = (nid >> 5) * 128, bn = (nid & 31) * 192;
  int tid = threadIdx.x, lane = tid & 63, wid = tid >> 6;
  int wr = wid >> 1, wc = wid & 1;
  int lq = lane & 15, lg = lane >> 4;
  f32x4 acc[4][6] = {};
  int nk = K >> 6;

  const bf16* Abase = A + (size_t)bm * K;
  const bf16* Bbase = B + (size_t)bn * K;
  size_t rowb = (size_t)K * 2;

  auto stage_a = [&](bf16* lds, int t){
    const char* g0 = (const char*)Abase + (size_t)t * 128;
    #pragma unroll
    for (int i = 0; i < 4; i++){
      int f = i * 256 + tid;
      int r = f >> 3, g = f & 7;
      gload_lds16(g0 + (size_t)r * rowb + (size_t)((g ^ (r & 7)) << 4),
                  (char*)lds + (size_t)f * 16);
    }
  };
  auto stage_b = [&](bf16* lds, int t){
    const char* g0 = (const char*)Bbase + (size_t)t * 128;
    #pragma unroll
    for (int i = 0; i < 6; i++){
      int f = i * 256 + tid;
      int r = f >> 3, g = f & 7;
      gload_lds16(g0 + (size_t)r * rowb + (size_t)((g ^ (r & 7)) << 4),
                  (char*)lds + (size_t)f * 16);
    }
  };

  stage_a(As[0], 0);
  stage_b(Bs[0], 0);

  for (int t = 0; t < nk; t++){
    if (t + 1 < nk){
      stage_a(As[(t + 1) & 1], t + 1);
      stage_b(Bs[(t + 1) & 1], t + 1);
      asm volatile("s_waitcnt vmcnt(10)" ::: "memory");
    } else {
      asm volatile("s_waitcnt vmcnt(0)" ::: "memory");
    }
    __builtin_amdgcn_s_barrier();
    const bf16* at = As[t & 1];
    const bf16* bt = Bs[t & 1];

    #pragma unroll
    for (int ks = 0; ks < 2; ks++){
      int gg = ks * 4 + lg;
      bf16x8 bfr[6];
      #pragma unroll
      for (int nf = 0; nf < 6; nf++){
        int rr = wc * 96 + nf * 16 + lq;
        bfr[nf] = *(const bf16x8*)(bt + rr * 64 + ((gg ^ (rr & 7)) << 3));
      }
      bf16x8 af[4];
      #pragma unroll
      for (int mf = 0; mf < 4; mf++){
        int rr = wr * 64 + mf * 16 + lq;
        af[mf] = *(const bf16x8*)(at + rr * 64 + ((gg ^ (rr & 7)) << 3));
      }
      __builtin_amdgcn_s_setprio(1);
      #pragma unroll
      for (int mf = 0; mf < 4; mf++)
        #pragma unroll
        for (int nf = 0; nf < 6; nf++)
          acc[mf][nf] = __builtin_amdgcn_mfma_f32_16x16x32_bf16(af[mf], bfr[nf], acc[mf][nf], 0, 0, 0);
      __builtin_amdgcn_s_setprio(0);
    }
    __builtin_amdgcn_s_barrier();
  }

  #pragma unroll
  for (int mf = 0; mf < 4; mf++){
    int mrow = bm + wr * 64 + mf * 16 + 4 * lg;
    #pragma unroll
    for (int nf = 0; nf < 6; nf++){
      int ncol = bn + wc * 96 + nf * 16 + lq;
      #pragma unroll
      for (int i = 0; i < 4; i++)
        C[(size_t)(mrow + i) * N + ncol] = acc[mf][nf][i];
    }
  }
}

// ---------------- bf16 GEMM: A[2048,K] x B[N,K]^T -> C[2048,N], BK=64, dbuf + counted vmcnt ----------------
__global__ __launch_bounds__(256, 2) void gemm_bt(const bf16* __restrict__ A, const bf16* __restrict__ B,
                                                  float* __restrict__ C, int N, int K){
  __shared__ bf16 As[2][128 * 64];
  __shared__ bf16 Bs[2][128 * 64];
  int bm = blockIdx.y * 128, bn = blockIdx.x * 128;
  int tid = threadIdx.x, wid = tid >> 6, lane = tid & 63;
  int wr = wid >> 1, wc = wid & 1;
  f32x4 acc[4][4] = {};
  int nk = K >> 6;
  stage_g8(A + (size_t)bm * K, (size_t)K * 2, As[0], tid);
  stage_g8(B + (size_t)bn * K, (size_t)K * 2, Bs[0], tid);
  for (int t = 0; t < nk; t++){
    if (t + 1 < nk){
      stage_g8(A + (size_t)bm * K + (t + 1) * 64, (size_t)K * 2, As[(t + 1) & 1], tid);
      stage_g8(B + (size_t)bn * K + (t + 1) * 64, (size_t)K * 2, Bs[(t + 1) & 1], tid);
      asm volatile("s_waitcnt vmcnt(8)" ::: "memory");
    } else {
      asm volatile("s_waitcnt vmcnt(0)" ::: "memory");
    }
    __builtin_amdgcn_s_barrier();
    const bf16* at = As[t & 1];
    const bf16* bt = Bs[t & 1];
    __builtin_amdgcn_s_setprio(1);
    #pragma unroll
    for (int ks2 = 0; ks2 < 2; ks2++){
      bf16x8 af[4], bfr[4];
      int g = ks2 * 4 + (lane >> 4);
      #pragma unroll
      for (int mf = 0; mf < 4; mf++){
        int rr = wr * 64 + mf * 16 + (lane & 15);
        af[mf] = *(const bf16x8*)(at + rr * 64 + ((g ^ (rr & 7)) << 3));
      }
      #pragma unroll
      for (int nf = 0; nf < 4; nf++){
        int rr = wc * 64 + nf * 16 + (lane & 15);
        bfr[nf] = *(const bf16x8*)(bt + rr * 64 + ((g ^ (rr & 7)) << 3));
      }
      #pragma unroll
      for (int mf = 0; mf < 4; mf++)
        #pragma unroll
        for (int nf = 0; nf < 4; nf++)
          acc[mf][nf] = __builtin_amdgcn_mfma_f32_16x16x32_bf16(af[mf], bfr[nf], acc[mf][nf], 0, 0, 0);
    }
    __builtin_amdgcn_s_setprio(0);
    __builtin_amdgcn_s_barrier();
  }
  int mrow = bm + wr * 64 + 4 * (lane >> 4);
  int ncol = bn + wc * 64 + (lane & 15);
  #pragma unroll
  for (int mf = 0; mf < 4; mf++)
    #pragma unroll
    for (int nf = 0; nf < 4; nf++)
      #pragma unroll
      for (int i = 0; i < 4; i++)
        C[(size_t)(mrow + mf * 16 + i) * N + ncol + nf * 16] = acc[mf][nf][i];
}

// ---------------- fused rope: Q (fq->f16) and K (fp32), one launch ----------------
__global__ __launch_bounds__(256) void rope_qk_k(const float* __restrict__ qkvraw, const float* __restrict__ cosT,
                                                 const float* __restrict__ sinT, f16* __restrict__ qf,
                                                 float* __restrict__ krope){
  int bid = blockIdx.x;
  int lane = threadIdx.x & 63;
  if (bid < 16384){
    int row = bid * 4 + (threadIdx.x >> 6);
    int hh = row >> 11, t = row & 2047;
    const float* qp = qkvraw + (size_t)t * NQKV + hh * HD;
    float q1 = qp[lane], q2 = qp[lane + 64];
    float c = cosT[t * 64 + lane], s = sinT[t * 64 + lane];
    float r1 = q1 * c - q2 * s;
    float r2 = q2 * c + q1 * s;
    float amax = fmaxf(fabsf(r1), fabsf(r2));
    #pragma unroll
    for (int d = 1; d < 64; d <<= 1) amax = fmaxf(amax, __shfl_xor(amax, d));
    float sc = fmaxf(amax, 1e-8f) / 127.f;
    const float kq = 0.08838834764831845f;
    f16* o = qf + ((size_t)hh * SEQ + t) * HD;
    o[lane]      = (f16)(fq_round(r1, sc) * kq);
    o[lane + 64] = (f16)(fq_round(r2, sc) * kq);
  } else {
    int row = (bid - 16384) * 4 + (threadIdx.x >> 6);
    int kvh = row >> 11, t = row & 2047;
    const float* kp = qkvraw + (size_t)t * NQKV + 4096 + kvh * HD;
    float k1 = kp[lane], k2 = kp[lane + 64];
    float c = cosT[t * 64 + lane], s = sinT[t * 64 + lane];
    float* o = krope + ((size_t)kvh * SEQ + t) * HD;
    o[lane]      = k1 * c - k2 * s;
    o[lane + 64] = k2 * c + k1 * s;
  }
}

// ---------------- fused per-channel absmax for K (rope'd) and V ----------------
__global__ __launch_bounds__(256) void kvmax_k(const float* __restrict__ krope, const float* __restrict__ qkvraw,
                                               float* __restrict__ kamax, float* __restrict__ vamax){
  int bid = blockIdx.x;
  int tid = threadIdx.x;
  if (bid < 64){
    int kvh = bid >> 3, slice = bid & 7;
    int c = tid & 127, rh = tid >> 7;
    const float* p = krope + ((size_t)kvh * SEQ + slice * 256 + rh) * HD + c;
    float a = 0.f;
    #pragma unroll 8
    for (int r = 0; r < 128; r++) a = fmaxf(a, fabsf(p[(size_t)r * 2 * HD]));
    atomicMax((int*)&kamax[kvh * 128 + c], __float_as_int(a));
  } else {
    int slice = bid - 64;
    const float4* p = (const float4*)qkvraw;
    float a0 = 0.f, a1 = 0.f, a2 = 0.f, a3 = 0.f;
    for (int r = 0; r < 32; r++){
      float4 v = p[(size_t)(slice * 32 + r) * 1536 + 1280 + tid];
      a0 = fmaxf(a0, fabsf(v.x)); a1 = fmaxf(a1, fabsf(v.y));
      a2 = fmaxf(a2, fabsf(v.z)); a3 = fmaxf(a3, fabsf(v.w));
    }
    atomicMax((int*)&vamax[tid * 4 + 0], __float_as_int(a0));
    atomicMax((int*)&vamax[tid * 4 + 1], __float_as_int(a1));
    atomicMax((int*)&vamax[tid * 4 + 2], __float_as_int(a2));
    atomicMax((int*)&vamax[tid * 4 + 3], __float_as_int(a3));
  }
}

// ---------------- fused quantize: K -> f16 [kvh][t][d]; V -> f16 transposed [kvh][d][t] ----------------
__global__ __launch_bounds__(256) void quant_kv_k(const float* __restrict__ krope, const float* __restrict__ qkvraw,
                                                  const float* __restrict__ kamax, const float* __restrict__ vamax,
                                                  f16* __restrict__ kf, f16* __restrict__ vt){
  __shared__ float tile[64][65];
  int bid = blockIdx.x;
  if (bid < 8192){
    int idx = bid * 256 + threadIdx.x;
    int d = idx & 127;
    int h = idx >> 18;
    float s = fmaxf(kamax[(h << 7) + d], 1e-8f) / 127.f;
    kf[idx] = (f16)fq_round(krope[idx], s);
  } else {
    int vid = bid - 8192;            // 0..511
    int t0 = (vid & 31) * 64;
    int c0 = (vid >> 5) * 64;
    int tx = threadIdx.x & 63, ty = threadIdx.x >> 6;
    #pragma unroll
    for (int i = 0; i < 16; i++){
      int r = i * 4 + ty;
      tile[r][tx] = qkvraw[(size_t)(t0 + r) * NQKV + 5120 + c0 + tx];
    }
    __syncthreads();
    #pragma unroll
    for (int i = 0; i < 16; i++){
      int dch = i * 4 + ty;
      int ch = c0 + dch;
      float s = fmaxf(vamax[ch], 1e-8f) / 127.f;
      vt[(size_t)ch * SEQ + t0 + tx] = (f16)fq_round(tile[tx][dch], s);
    }
  }
}

// ---------------- attention: swapped QK^T + staged LDS; wave-uniform mask paths; e'=exp(s-m+ln127) ----------------
__global__ __launch_bounds__(256, 2) void attn_k(const f16* __restrict__ qf, const f16* __restrict__ kf,
                                                 const f16* __restrict__ vt, float* __restrict__ aout){
  int pr = blockIdx.x;            // 0..15
  int hh = blockIdx.y;            // 0..31
  int qtA = pr, qtB = 31 - pr;
  int kvh = hh >> 2;
  int tid = threadIdx.x, wid = tid >> 6, lane = tid & 63;
  int lq = lane & 15, lg = lane >> 4;

  __shared__ f16 ks[2][64 * 128];
  __shared__ f16 vs[2][128 * 64];
  __shared__ f16 ps[4][16][80];

  f16x8 bqA[4], bqB[4];
  {
    const f16* qbA = qf + ((size_t)hh * SEQ + qtA * 64 + wid * 16 + lq) * HD + lg * 8;
    const f16* qbB = qf + ((size_t)hh * SEQ + qtB * 64 + wid * 16 + lq) * HD + lg * 8;
    #pragma unroll
    for (int kk = 0; kk < 4; kk++){
      bqA[kk] = *(const f16x8*)(qbA + kk * 32);
      bqB[kk] = *(const f16x8*)(qbB + kk * 32);
    }
  }
  int qgA = qtA * 64 + wid * 16 + lq;
  int qgB = qtB * 64 + wid * 16 + lq;

  const f16* kbase = kf + (size_t)kvh * SEQ * HD;
  const f16* vbase = vt + (size_t)kvh * HD * SEQ;
  int nkb = qtB + 1;

  // ---- pass 1: exact per-row max (unmasked fast path off-diagonal) ----
  float mxA = -1e30f, mxB = -1e30f;
  stage_g16(kbase, (size_t)HD * 2, ks[0], tid);
  for (int kb = 0; kb < nkb; kb++){
    if (kb + 1 < nkb){
      stage_g16(kbase + (size_t)(kb + 1) * 64 * HD, (size_t)HD * 2, ks[(kb + 1) & 1], tid);
      asm volatile("s_waitcnt vmcnt(4)" ::: "memory");
    } else {
      asm volatile("s_waitcnt vmcnt(0)" ::: "memory");
    }
    __builtin_amdgcn_s_barrier();
    const f16* kt = ks[kb & 1];
    bool doA = (kb <= qtA);
    bool diagB = (kb == qtB), diagA = (kb == qtA);
    __builtin_amdgcn_s_setprio(1);
    #pragma unroll
    for (int nf = 0; nf < 4; nf++){
      int rr = nf * 16 + lq;
      f16x8 ka[4];
      #pragma unroll
      for (int kk = 0; kk < 4; kk++)
        ka[kk] = *(const f16x8*)(kt + rr * 128 + (((kk * 4 + lg) ^ (rr & 15)) << 3));
      int k0 = kb * 64 + nf * 16 + lg * 4;
      f32x4 sB = {0.f, 0.f, 0.f, 0.f};
      #pragma unroll
      for (int kk = 0; kk < 4; kk++) sB = __builtin_amdgcn_mfma_f32_16x16x32_f16(ka[kk], bqB[kk], sB, 0, 0, 0);
      if (!diagB){
        #pragma unroll
        for (int i = 0; i < 4; i++) mxB = fmaxf(mxB, sB[i]);
      } else {
        #pragma unroll
        for (int i = 0; i < 4; i++)
          if (k0 + i <= qgB) mxB = fmaxf(mxB, sB[i]);
      }
      if (doA){
        f32x4 sA = {0.f, 0.f, 0.f, 0.f};
        #pragma unroll
        for (int kk = 0; kk < 4; kk++) sA = __builtin_amdgcn_mfma_f32_16x16x32_f16(ka[kk], bqA[kk], sA, 0, 0, 0);
        if (!diagA){
          #pragma unroll
          for (int i = 0; i < 4; i++) mxA = fmaxf(mxA, sA[i]);
        } else {
          #pragma unroll
          for (int i = 0; i < 4; i++)
            if (k0 + i <= qgA) mxA = fmaxf(mxA, sA[i]);
        }
      }
    }
    __builtin_amdgcn_s_setprio(0);
    __builtin_amdgcn_s_barrier();
  }
  mxB = fmaxf(mxB, __shfl_xor(mxB, 16)); mxB = fmaxf(mxB, __shfl_xor(mxB, 32));
  mxA = fmaxf(mxA, __shfl_xor(mxA, 16)); mxA = fmaxf(mxA, __shfl_xor(mxA, 32));
  float mB2 = mxB - LN127;   // e' = exp(s - mB2) = 127*exp(s - m)
  float mA2 = mxA - LN127;

  // ---- pass 2: integer P = rint(e'), l' = sum e' (=127 l), PV ----
  float lsA = 0.f, lsB = 0.f;
  f32x4 oA[8] = {}, oB[8] = {};
  stage_g16(kbase, (size_t)HD * 2, ks[0], tid);
  stage_g8(vbase, (size_t)SEQ * 2, vs[0], tid);
  for (int kb = 0; kb < nkb; kb++){
    if (kb + 1 < nkb){
      stage_g16(kbase + (size_t)(kb + 1) * 64 * HD, (size_t)HD * 2, ks[(kb + 1) & 1], tid);
      stage_g8(vbase + (kb + 1) * 64, (size_t)SEQ * 2, vs[(kb + 1) & 1], tid);
      asm volatile("s_waitcnt vmcnt(8)" ::: "memory");
    } else {
      asm volatile("s_waitcnt vmcnt(0)" ::: "memory");
    }
    __builtin_amdgcn_s_barrier();
    const f16* kt = ks[kb & 1];
    const f16* vtile = vs[kb & 1];
    bool doA = (kb <= qtA);
    bool diagB = (kb == qtB), diagA = (kb == qtA);
    f32x4 saccA[4];

    __builtin_amdgcn_s_setprio(1);
    #pragma unroll
    for (int nf = 0; nf < 4; nf++){
      int rr = nf * 16 + lq;
      f16x8 ka[4];
      #pragma unroll
      for (int kk = 0; kk < 4; kk++)
        ka[kk] = *(const f16x8*)(kt + rr * 128 + (((kk * 4 + lg) ^ (rr & 15)) << 3));
      f32x4 sB = {0.f, 0.f, 0.f, 0.f};
      #pragma unroll
      for (int kk = 0; kk < 4; kk++) sB = __builtin_amdgcn_mfma_f32_16x16x32_f16(ka[kk], bqB[kk], sB, 0, 0, 0);
      if (doA){
        f32x4 sA = {0.f, 0.f, 0.f, 0.f};
        #pragma unroll
        for (int kk = 0; kk < 4; kk++) sA = __builtin_amdgcn_mfma_f32_16x16x32_f16(ka[kk], bqA[kk], sA, 0, 0, 0);
        saccA[nf] = sA;
      }
      int k0 = kb * 64 + nf * 16 + lg * 4;
      f16x4 pB4;
      if (!diagB){
        #pragma unroll
        for (int i = 0; i < 4; i++){
          float e = __expf(sB[i] - mB2);
          lsB += e;
          pB4[i] = (f16)rintf(e);
        }
      } else {
        #pragma unroll
        for (int i = 0; i < 4; i++){
          float e = (k0 + i <= qgB) ? __expf(sB[i] - mB2) : 0.f;
          lsB += e;
          pB4[i] = (f16)rintf(e);
        }
      }
      *(f16x4*)&ps[wid][lq][nf * 16 + lg * 4] = pB4;
    }
    {
      f16x8 pa0 = *(const f16x8*)&ps[wid][lq][lg * 8];
      f16x8 pa1 = *(const f16x8*)&ps[wid][lq][32 + lg * 8];
      #pragma unroll
      for (int nf2 = 0; nf2 < 8; nf2++){
        int rr = nf2 * 16 + lq;
        f16x8 v0 = *(const f16x8*)(vtile + rr * 64 + (((lg) ^ (rr & 7)) << 3));
        f16x8 v1 = *(const f16x8*)(vtile + rr * 64 + (((4 + lg) ^ (rr & 7)) << 3));
        oB[nf2] = __builtin_amdgcn_mfma_f32_16x16x32_f16(pa0, v0, oB[nf2], 0, 0, 0);
        oB[nf2] = __builtin_amdgcn_mfma_f32_16x16x32_f16(pa1, v1, oB[nf2], 0, 0, 0);
      }
    }
    if (doA){
      #pragma unroll
      for (int nf = 0; nf < 4; nf++){
        int k0 = kb * 64 + nf * 16 + lg * 4;
        f16x4 pA4;
        if (!diagA){
          #pragma unroll
          for (int i = 0; i < 4; i++){
            float e = __expf(saccA[nf][i] - mA2);
            lsA += e;
            pA4[i] = (f16)rintf(e);
          }
        } else {
          #pragma unroll
          for (int i = 0; i < 4; i++){
            float e = (k0 + i <= qgA) ? __expf(saccA[nf][i] - mA2) : 0.f;
            lsA += e;
            pA4[i] = (f16)rintf(e);
          }
        }
        *(f16x4*)&ps[wid][lq][nf * 16 + lg * 4] = pA4;
      }
      f16x8 pa0 = *(const f16x8*)&ps[wid][lq][lg * 8];
      f16x8 pa1 = *(const f16x8*)&ps[wid][lq][32 + lg * 8];
      #pragma unroll
      for (int nf2 = 0; nf2 < 8; nf2++){
        int rr = nf2 * 16 + lq;
        f16x8 v0 = *(const f16x8*)(vtile + rr * 64 + (((lg) ^ (rr & 7)) << 3));
        f16x8 v1 = *(const f16x8*)(vtile + rr * 64 + (((4 + lg) ^ (rr & 7)) << 3));
        oA[nf2] = __builtin_amdgcn_mfma_f32_16x16x32_f16(pa0, v0, oA[nf2], 0, 0, 0);
        oA[nf2] = __builtin_amdgcn_mfma_f32_16x16x32_f16(pa1, v1, oA[nf2], 0, 0, 0);
      }
    }
    __builtin_amdgcn_s_setprio(0);
    __builtin_amdgcn_s_barrier();
  }

  lsB += __shfl_xor(lsB, 16); lsB += __shfl_xor(lsB, 32);
  lsA += __shfl_xor(lsA, 16); lsA += __shfl_xor(lsA, 32);

  // epilogue: scale = 1/l' (= 1/(127 l)); per-row fq over HD
  auto epilogue = [&](f32x4* oacc, float lrow, int qt){
    float inv[4];
    #pragma unroll
    for (int i = 0; i < 4; i++)
      inv[i] = 1.f / __shfl(lrow, lg * 4 + i);
    float am[4] = {0.f, 0.f, 0.f, 0.f};
    #pragma unroll
    for (int nf2 = 0; nf2 < 8; nf2++)
      #pragma unroll
      for (int i = 0; i < 4; i++)
        am[i] = fmaxf(am[i], fabsf(oacc[nf2][i] * inv[i]));
    #pragma unroll
    for (int i = 0; i < 4; i++){
      float a = am[i];
      #pragma unroll
      for (int d = 1; d < 16; d <<= 1) a = fmaxf(a, __shfl_xor(a, d));
      am[i] = a;
    }
    #pragma unroll
    for (int i = 0; i < 4; i++){
      float so = fmaxf(am[i], 1e-8f) / 127.f;
      int row = qt * 64 + wid * 16 + lg * 4 + i;
      float* op = aout + ((size_t)hh * SEQ + row) * HD + lq;
      #pragma unroll
      for (int nf2 = 0; nf2 < 8; nf2++){
        float v = oacc[nf2][i] * inv[i];
        op[nf2 * 16] = fq_round(v, so);
      }
    }
  };
  epilogue(oB, lsB, qtB);
  epilogue(oA, lsA, qtA);
}

// ---------------- epilogue: gather heads, *o_scale2, fq(out - qb2) + qb2 -> bf16 (float4) ----------------
__global__ __launch_bounds__(256) void epi_k(const float* __restrict__ aout, const float* __restrict__ osc,
                                             const float* __restrict__ qb2, bf16* __restrict__ act){
  int t = blockIdx.x, tid = threadIdx.x;
  const float4* osc4 = (const float4*)osc;
  const float4* qb4  = (const float4*)qb2;
  float4 z[4]; float amax = 0.f;
  #pragma unroll
  for (int i = 0; i < 4; i++){
    int o4 = tid + i * 256;          // float4 index; elems o4*4..o4*4+3 (same head block)
    int o = o4 * 4;
    int h = o >> 7, d = o & 127;
    float4 y = *(const float4*)(aout + ((size_t)h * SEQ + t) * HD + d);
    float4 sc = osc4[o4], bb = qb4[o4];
    float4 zz = { y.x * sc.x - bb.x, y.y * sc.y - bb.y, y.z * sc.z - bb.z, y.w * sc.w - bb.w };
    z[i] = zz;
    amax = fmaxf(amax, fmaxf(fmaxf(fabsf(zz.x), fabsf(zz.y)), fmaxf(fabsf(zz.z), fabsf(zz.w))));
  }
  #pragma unroll
  for (int d = 1; d < 64; d <<= 1) amax = fmaxf(amax, __shfl_xor(amax, d));
  __shared__ float red[4];
  if ((tid & 63) == 0) red[tid >> 6] = amax;
  __syncthreads();
  amax = fmaxf(fmaxf(red[0], red[1]), fmaxf(red[2], red[3]));
  float s = fmaxf(amax, 1e-8f) / 127.f;
  bf16x4* ab = (bf16x4*)(act + (size_t)t * HID);
  #pragma unroll
  for (int i = 0; i < 4; i++){
    int o4 = tid + i * 256;
    float4 bb = qb4[o4];
    bf16x4 o = { (bf16)(fq_round(z[i].x, s) + bb.x),
                 (bf16)(fq_round(z[i].y, s) + bb.y),
                 (bf16)(fq_round(z[i].z, s) + bb.z),
                 (bf16)(fq_round(z[i].w, s) + bb.w) };
    ab[o4] = o;
  }
}

extern "C" void kernel_launch(void* const* d_in, const int* in_sizes, int n_in,
                              void* d_out, int out_size, void* d_ws, size_t ws_size,
                              hipStream_t stream) {
  const float* hidden = (const float*)d_in[0];
  const int*   pos    = (const int*)d_in[1];
  const float* Wq     = (const float*)d_in[2];
  const float* Wk     = (const float*)d_in[3];
  const float* Wv     = (const float*)d_in[4];
  const float* Wo     = (const float*)d_in[5];
  const float* qb1    = (const float*)d_in[6];
  const float* qb2    = (const float*)d_in[7];
  const float* osc    = (const float*)d_in[8];
  float* out = (float*)d_out;

  char* w = (char*)d_ws;
  size_t off = 0;
  auto take = [&](size_t b) -> char* {
    char* p = w + off;
    off += (b + 255) & ~(size_t)255;
    return p;
  };
  bf16* qkvW  = (bf16*)take((size_t)NQKV * HID * 2);     // [6144][4096]
  bf16* WoB   = (bf16*)take((size_t)HID * HID * 2);
  bf16* hsB   = (bf16*)take((size_t)SEQ * HID * 2);
  float* cosT = (float*)take((size_t)SEQ * 64 * 4);
  float* sinT = (float*)take((size_t)SEQ * 64 * 4);
  float* qkv_raw = (float*)take((size_t)SEQ * NQKV * 4); // [2048][6144]
  float* krope = (float*)take((size_t)NKV * SEQ * HD * 4);
  f16* qf  = (f16*)take((size_t)NH * SEQ * HD * 2);
  f16* kf  = (f16*)take((size_t)NKV * SEQ * HD * 2);
  f16* vtf = (f16*)take((size_t)NKV * HD * SEQ * 2);
  float* kvamax = (float*)take(2048 * 4);
  float* kamax = kvamax, *vamax = kvamax + 1024;
  float* aout = qkv_raw;   // alias: qkv_raw dead after rope/quant kernels
  bf16*  act  = hsB;       // alias: hs dead after QKV GEMM

  hipMemsetAsync(kvamax, 0, 2048 * sizeof(float), stream);
  preproc_k<<<43520, 256, 0, stream>>>(Wq, Wk, Wv, Wo, qkvW, WoB, pos, cosT, sinT, hidden, qb1, hsB);
  gemm9<<<dim3(32, 16), 256, 0, stream>>>(hsB, qkvW, qkv_raw, NQKV, 4096);
  rope_qk_k<<<20480, 256, 0, stream>>>(qkv_raw, cosT, sinT, qf, krope);
  kvmax_k<<<128, 256, 0, stream>>>(krope, qkv_raw, kamax, vamax);
  quant_kv_k<<<8704, 256, 0, stream>>>(krope, qkv_raw, kamax, vamax, kf, vtf);
  attn_k<<<dim3(16, 32), 256, 0, stream>>>(qf, kf, vtf, aout);
  epi_k<<<2048, 256, 0, stream>>>(aout, osc, qb2, act);
  gemm_bt<<<dim3(32, 16), 256, 0, stream>>>(act, WoB, out, 4096, 4096);
}